// Round 11
// baseline (3772.227 us; speedup 1.0000x reference)
//
#include <hip/hip_runtime.h>
#include <cstdint>
#include <cstddef>

typedef _Float16 half2_t __attribute__((ext_vector_type(2)));
typedef _Float16 half4_t __attribute__((ext_vector_type(4)));
typedef _Float16 half8_t __attribute__((ext_vector_type(8)));
typedef float    float4_t __attribute__((ext_vector_type(4)));

#define CAPLEN 65
#define PTLD 200       // P_T row stride in halfs (196 used)

#define AT_LD(p)     __hip_atomic_load((p), __ATOMIC_RELAXED, __HIP_MEMORY_SCOPE_AGENT)
#define AT_ST(p, v)  __hip_atomic_store((p), (v), __ATOMIC_RELAXED, __HIP_MEMORY_SCOPE_AGENT)

#if defined(__has_builtin)
#if __has_builtin(__builtin_amdgcn_fdot2)
#define HAS_FDOT2 1
#endif
#endif

__device__ __forceinline__ float fdot2f(half2_t a, half2_t b, float c) {
#ifdef HAS_FDOT2
  return __builtin_amdgcn_fdot2(a, b, c, false);
#else
  return c + (float)a[0]*(float)b[0] + (float)a[1]*(float)b[1];
#endif
}

__device__ __forceinline__ float fast_tanh(float x) {
  float e = __expf(2.f*x);
  return 1.f - 2.f/(e + 1.f);
}
__device__ __forceinline__ float fast_sig(float x) {
  return 1.f/(1.f + __expf(-x));
}

// ---------------- mega setup: all converts + bias + gather + tag fill ----------------
//   [0,C1)   cvt Wenc      [C1,C2) cvt Wdec     [C2,C3) cvt W_ih
//   [C3,C4)  cvt W_hh      [C4,C5) cvt Wfc      [C5,C6) cvt imgf
//   [C6,C7)  gather emb -> X_h (fp16)
//   [C7,C8)  bias quads (bsum = b_ih + b_hh)
//   [C8,C9)  invalidate hpub64 parity-1 (parity-0 fully written by init_state_k)
//   [C9,C10) invalidate hwpub64 parity-1 (parity-0 fully written by init_state_k)
#define MS_C1 65536
#define MS_C2 131072
#define MS_C3 655360
#define MS_C4 917504
#define MS_C5 5013504
#define MS_C6 5816320
#define MS_C7 6078464
#define MS_C8 6078976
#define MS_C9 6087168
#define MS_C10 6218240

__device__ __forceinline__ void cvt_quad(const float* __restrict__ s,
                                         _Float16* __restrict__ d, int q) {
  float4 v = ((const float4*)s)[q];
  half4_t h;
  h[0] = (_Float16)v.x; h[1] = (_Float16)v.y; h[2] = (_Float16)v.z; h[3] = (_Float16)v.w;
  ((half4_t*)d)[q] = h;
}

__global__ void mega_setup_k(
    const float* __restrict__ Wenc, _Float16* __restrict__ Wenc_h,
    const float* __restrict__ Wdec, _Float16* __restrict__ Wdec_h,
    const float* __restrict__ Wih,  _Float16* __restrict__ Wih_h,
    const float* __restrict__ Whh,  _Float16* __restrict__ Whh_h,
    const float* __restrict__ Wfc,  _Float16* __restrict__ Wfc_h,
    const float* __restrict__ imgf, _Float16* __restrict__ imgf_h,
    const float* __restrict__ emb,  const int* __restrict__ cap,
    _Float16* __restrict__ X_h,
    const float* __restrict__ b_ih, const float* __restrict__ b_hh,
    float* __restrict__ bsum,
    unsigned long long* __restrict__ hpub64,
    unsigned long long* __restrict__ hwpub64) {
  int stride = gridDim.x*blockDim.x;
  for (int i = blockIdx.x*blockDim.x + threadIdx.x; i < MS_C10; i += stride) {
    if (i < MS_C1) {
      cvt_quad(Wenc, Wenc_h, i);
    } else if (i < MS_C2) {
      cvt_quad(Wdec, Wdec_h, i - MS_C1);
    } else if (i < MS_C3) {
      cvt_quad(Wih, Wih_h, i - MS_C2);
    } else if (i < MS_C4) {
      cvt_quad(Whh, Whh_h, i - MS_C3);
    } else if (i < MS_C5) {
      cvt_quad(Wfc, Wfc_h, i - MS_C4);
    } else if (i < MS_C6) {
      cvt_quad(imgf, imgf_h, i - MS_C5);
    } else if (i < MS_C7) {
      int g = i - MS_C6;               // 2048 rows x 128 quads
      int row = g >> 7, q = g & 127;
      int t = row >> 5, b = row & 31;
      int tok = cap[b*CAPLEN + t];
      float4 v = ((const float4*)(emb + (size_t)tok*512))[q];
      half4_t h;
      h[0] = (_Float16)v.x; h[1] = (_Float16)v.y; h[2] = (_Float16)v.z; h[3] = (_Float16)v.w;
      *(half4_t*)(X_h + (size_t)row*512 + q*4) = h;
    } else if (i < MS_C8) {
      int q = i - MS_C7;               // 512 quads of bias
      float4 a = ((const float4*)b_ih)[q];
      float4 b = ((const float4*)b_hh)[q];
      float4 o; o.x = a.x+b.x; o.y = a.y+b.y; o.z = a.z+b.z; o.w = a.w+b.w;
      ((float4*)bsum)[q] = o;
    } else if (i < MS_C9) {
      hpub64[8192 + (i - MS_C8)] = ~0ull;    // parity-1 h words
    } else {
      hwpub64[131072 + (i - MS_C9)] = ~0ull; // parity-1 hw words
    }
  }
}

// feat_mean -> h0 (tag-0 parity-0 words) + hW0 partials (r=0 full, r=1..7 zero), c0
__global__ void init_state_k(const float* __restrict__ imgf,
                             const float* __restrict__ Wh0, const float* __restrict__ bh0,
                             const float* __restrict__ Wc0, const float* __restrict__ bc0,
                             const float* __restrict__ Wdec,
                             float* __restrict__ c_state,
                             unsigned long long* __restrict__ hpub64,
                             unsigned long long* __restrict__ hwpub64) {
  __shared__ float fm[512];
  __shared__ float hsh[512];
  int b = blockIdx.x, tid = threadIdx.x;
  for (int dI = tid; dI < 512; dI += 256) {
    float s = 0.f;
    const float* p = imgf + ((size_t)b*196)*512 + dI;
    for (int n = 0; n < 196; n++) s += p[(size_t)n*512];
    fm[dI] = s * (1.f/196.f);
  }
  __syncthreads();
  for (int dI = tid; dI < 512; dI += 256) {
    const float* wh = Wh0 + (size_t)dI*512;
    const float* wc = Wc0 + (size_t)dI*512;
    float h = bh0[dI], c = bc0[dI];
    for (int k = 0; k < 512; k++) { h += fm[k]*wh[k]; c += fm[k]*wc[k]; }
    hsh[dI] = h;
    c_state[b*512 + dI] = c;
  }
  __syncthreads();
  {
    half2_t h2; h2[0] = (_Float16)hsh[2*tid]; h2[1] = (_Float16)hsh[2*tid+1];
    union { half2_t h; unsigned u; } cv; cv.h = h2;
    hpub64[(size_t)b*256 + tid] = (unsigned long long)cv.u;   // tag 0, parity 0
  }
  // hW0[d] = Wdec[d,:] . h0 (fp32), published as r=0 partial; r=1..7 zero (tag 0)
  for (int d = tid; d < 512; d += 256) {
    const float* wd = Wdec + (size_t)d*512;
    float s = 0.f;
    for (int k = 0; k < 512; k++) s += wd[k]*hsh[k];
    union { float f; unsigned u; } cv; cv.f = s;
    unsigned long long* base = hwpub64 + ((size_t)b*512 + d)*8;
    base[0] = (unsigned long long)cv.u;
    #pragma unroll
    for (int rr = 1; rr < 8; rr++) base[rr] = 0ull;
  }
}

// ---- GEMM bodies (device functions for the merged setup-GEMM kernel) ----
// C[b][row][n] = sum_k A[row][k] * imgf[b][n][k]   (fp16 out, ldc=PTLD)
__device__ __forceinline__ void gemm_pt_body(const _Float16* __restrict__ A, int lda,
    const _Float16* __restrict__ Bimg, _Float16* __restrict__ Cpt, int mrows,
    int bx, int by, int bz, int tid) {
  const _Float16* B = Bimg + (size_t)bz*196*512;
  _Float16* C = Cpt + (size_t)bz*mrows*PTLD;
  int wave = tid >> 6, lane = tid & 63;
  int m0 = by*128 + (wave >> 1)*64;
  int n0 = bx*128 + (wave & 1)*64;
  int lr = lane & 15, quad = lane >> 4;
  float4_t acc[4][4];
  #pragma unroll
  for (int i = 0; i < 4; i++)
    #pragma unroll
    for (int j = 0; j < 4; j++)
      acc[i][j] = (float4_t){0.f, 0.f, 0.f, 0.f};
  const _Float16* Ap = A + (size_t)(m0 + lr)*lda + quad*8;
  const _Float16* Bp = B + (size_t)(n0 + lr)*512 + quad*8;
  for (int k0 = 0; k0 < 512; k0 += 32) {
    half8_t af[4], bf[4];
    #pragma unroll
    for (int i = 0; i < 4; i++) af[i] = *(const half8_t*)(Ap + (size_t)i*16*lda + k0);
    #pragma unroll
    for (int i = 0; i < 4; i++) bf[i] = *(const half8_t*)(Bp + (size_t)i*16*512 + k0);
    #pragma unroll
    for (int mi = 0; mi < 4; mi++)
      #pragma unroll
      for (int ni = 0; ni < 4; ni++)
        acc[mi][ni] = __builtin_amdgcn_mfma_f32_16x16x32_f16(af[mi], bf[ni], acc[mi][ni], 0, 0, 0);
  }
  #pragma unroll
  for (int mi = 0; mi < 4; mi++) {
    #pragma unroll
    for (int ni = 0; ni < 4; ni++) {
      int col = n0 + ni*16 + lr;
      if (col < PTLD) {
        #pragma unroll
        for (int r = 0; r < 4; r++) {
          int row = m0 + mi*16 + quad*4 + r;
          C[(size_t)row*PTLD + col] = (_Float16)acc[mi][ni][r];
        }
      }
    }
  }
}

// C = A * B^T, fp16 out (no bias)
__device__ __forceinline__ void gemm_ab1_body(const _Float16* __restrict__ A, int lda,
    const _Float16* __restrict__ B, int ldb, _Float16* __restrict__ C, int ldc,
    int K, int bx, int by, int tid) {
  int wave = tid >> 6, lane = tid & 63;
  int m0 = by*128 + (wave >> 1)*64;
  int n0 = bx*128 + (wave & 1)*64;
  int lr = lane & 15, quad = lane >> 4;
  float4_t acc[4][4];
  #pragma unroll
  for (int i = 0; i < 4; i++)
    #pragma unroll
    for (int j = 0; j < 4; j++)
      acc[i][j] = (float4_t){0.f, 0.f, 0.f, 0.f};
  const _Float16* Ap = A + (size_t)(m0 + lr)*lda + quad*8;
  const _Float16* Bp = B + (size_t)(n0 + lr)*ldb + quad*8;
  for (int k0 = 0; k0 < K; k0 += 32) {
    half8_t af[4], bf[4];
    #pragma unroll
    for (int i = 0; i < 4; i++) af[i] = *(const half8_t*)(Ap + (size_t)i*16*lda + k0);
    #pragma unroll
    for (int i = 0; i < 4; i++) bf[i] = *(const half8_t*)(Bp + (size_t)i*16*ldb + k0);
    #pragma unroll
    for (int mi = 0; mi < 4; mi++)
      #pragma unroll
      for (int ni = 0; ni < 4; ni++)
        acc[mi][ni] = __builtin_amdgcn_mfma_f32_16x16x32_f16(af[mi], bf[ni], acc[mi][ni], 0, 0, 0);
  }
  #pragma unroll
  for (int mi = 0; mi < 4; mi++) {
    #pragma unroll
    for (int ni = 0; ni < 4; ni++) {
      int col = n0 + ni*16 + lr;
      #pragma unroll
      for (int r = 0; r < 4; r++) {
        int row = m0 + mi*16 + quad*4 + r;
        C[(size_t)row*ldc + col] = (_Float16)acc[mi][ni][r];
      }
    }
  }
}

// C = A * B^T + bias, fp32 out
__device__ __forceinline__ void gemm_ab0_body(const _Float16* __restrict__ A, int lda,
    const _Float16* __restrict__ B, int ldb, float* __restrict__ C, int ldc,
    const float* __restrict__ bias, int K, int bx, int by, int tid) {
  int wave = tid >> 6, lane = tid & 63;
  int m0 = by*128 + (wave >> 1)*64;
  int n0 = bx*128 + (wave & 1)*64;
  int lr = lane & 15, quad = lane >> 4;
  float4_t acc[4][4];
  #pragma unroll
  for (int i = 0; i < 4; i++)
    #pragma unroll
    for (int j = 0; j < 4; j++)
      acc[i][j] = (float4_t){0.f, 0.f, 0.f, 0.f};
  const _Float16* Ap = A + (size_t)(m0 + lr)*lda + quad*8;
  const _Float16* Bp = B + (size_t)(n0 + lr)*ldb + quad*8;
  for (int k0 = 0; k0 < K; k0 += 32) {
    half8_t af[4], bf[4];
    #pragma unroll
    for (int i = 0; i < 4; i++) af[i] = *(const half8_t*)(Ap + (size_t)i*16*lda + k0);
    #pragma unroll
    for (int i = 0; i < 4; i++) bf[i] = *(const half8_t*)(Bp + (size_t)i*16*ldb + k0);
    #pragma unroll
    for (int mi = 0; mi < 4; mi++)
      #pragma unroll
      for (int ni = 0; ni < 4; ni++)
        acc[mi][ni] = __builtin_amdgcn_mfma_f32_16x16x32_f16(af[mi], bf[ni], acc[mi][ni], 0, 0, 0);
  }
  #pragma unroll
  for (int mi = 0; mi < 4; mi++) {
    #pragma unroll
    for (int ni = 0; ni < 4; ni++) {
      int col = n0 + ni*16 + lr;
      float bv = bias[col];
      #pragma unroll
      for (int r = 0; r < 4; r++) {
        int row = m0 + mi*16 + quad*4 + r;
        C[(size_t)row*ldc + col] = acc[mi][ni][r] + bv;
      }
    }
  }
}

// merged setup GEMMs: [0,196) fproj, [196,1220) P_T, [1220,1476) Xg
__global__ void __launch_bounds__(256) setup_gemms_k(
    const _Float16* __restrict__ Wenc_h, const _Float16* __restrict__ Wih_h,
    const _Float16* __restrict__ imgf_h, const _Float16* __restrict__ X_h,
    _Float16* __restrict__ fproj_h, _Float16* __restrict__ P_T,
    float* __restrict__ Xg, const float* __restrict__ bsum) {
  int bid = blockIdx.x, tid = threadIdx.x;
  if (bid < 196) {
    // fproj[b*196+n][d] = imgf . Wenc^T : M=6272, N=512
    gemm_ab1_body(imgf_h, 512, Wenc_h, 512, fproj_h, 512, 512, bid & 3, bid >> 2, tid);
  } else if (bid < 1220) {
    int l = bid - 196;
    gemm_pt_body(Wih_h + 512, 1024, imgf_h, P_T, 2048, l & 1, (l >> 1) & 15, l >> 5, tid);
  } else {
    int l = bid - 1220;
    gemm_ab0_body(X_h, 512, Wih_h, 1024, Xg, 2048, bsum, 512, l & 15, l >> 4, tid);
  }
}

// ---- persistent recurrence: ONE exchange round per step ----
// b-grouped XCD mapping: r=(bid>>3)&7, b=(bid&7)|((bid>>6)<<3); group b's 8
// blocks share bid%8 -> one XCD; per-XCD L2 set = 4x fproj (800KB) + Whh (2MB).
// Per step: poll h(t) -> gacc=Xg+Whh.h (hides hw propagation) -> poll 8 split-K
// hW partials -> full hW -> REPLICATED e+softmax (no 2nd exchange) -> alpha.P
// (LDS) -> pointwise -> publish h-slice + partial_hW(t+1) (Wdec k-slice PINNED
// in 16 VGPRs -> zero per-step weight traffic for the partial).
__global__ void __launch_bounds__(512) loop_k(
    const _Float16* __restrict__ Wdec_h,   // [512][512] row-major [d][k]
    const _Float16* __restrict__ Whh_h,    // [2048][512]
    const _Float16* __restrict__ fproj_h,  // [32][196][512]
    const _Float16* __restrict__ P_T,      // [32][2048][PTLD]
    const float*    __restrict__ Xg,       // [64*32][2048]
    const float*    __restrict__ v_att,    // [512]
    const float*    __restrict__ c_init,   // [32][512]
    unsigned long long* __restrict__ hpub64, // [2][32][256] (tag|half2)
    unsigned long long* __restrict__ hwpub64,// [2][32][512][8] (tag|float)
    _Float16*       __restrict__ H_h,      // [64*32][512]
    float*          __restrict__ out_alpha)// [32][64][196]
{
  __shared__ _Float16 P_lds[98*256*2];     // [n2][row][2] half2-interleaved, 100352B
  __shared__ __align__(16) unsigned hl_u[256]; // h as packed half2
  __shared__ float hwl[512];               // full hW
  __shared__ float vlf[512];
  __shared__ float e_l[196];
  __shared__ float redA[8];
  __shared__ float redB[8];
  __shared__ float sa[256];
  __shared__ float sm2[512];
  __shared__ float hnl[64];
  __shared__ _Float16 Hbuf[64*64];         // own h slice per step, 8192B
  __shared__ float abuf[25*64];            // own alpha slice [ln][t], 6400B
  int bid = blockIdx.x, tid = threadIdx.x;
  int r = (bid >> 3) & 7;
  int b = (bid & 7) | ((bid >> 6) << 3);
  int row = tid & 255, half = tid >> 8;
  int typ = row >> 6, dl = row & 63;
  int grow = typ*512 + r*64 + dl;          // gate row owned by (thread row)
  int lane = tid & 63;

  vlf[tid] = v_att[tid];
  float c_reg = (tid < 64) ? c_init[b*512 + r*64 + tid] : 0.f;

  // pinned Wdec k-slice: thread d=tid owns Wdec[d][r*64 .. r*64+64) (t-invariant)
  half8_t wdec_reg[8];
  {
    const half8_t* wp = (const half8_t*)(Wdec_h + (size_t)tid*512 + r*64);
    #pragma unroll
    for (int j = 0; j < 8; j++) wdec_reg[j] = wp[j];
  }

  // one-time staging: P rows (tid<256)
  if (tid < 256) {
    const _Float16* pp = P_T + ((size_t)b*2048 + grow)*PTLD;
    half2_t* P2 = (half2_t*)P_lds;
    for (int k8 = 0; k8 < 24; k8++) {
      half8_t v8 = *(const half8_t*)(pp + k8*8);
      #pragma unroll
      for (int j2 = 0; j2 < 4; j2++) {
        half2_t h2; h2[0] = v8[2*j2]; h2[1] = v8[2*j2+1];
        P2[(k8*4 + j2)*256 + row] = h2;
      }
    }
    half4_t v4 = *(const half4_t*)(pp + 192);
    half2_t a2; a2[0] = v4[0]; a2[1] = v4[1];
    half2_t b2; b2[0] = v4[2]; b2[1] = v4[3];
    P2[96*256 + row] = a2;
    P2[97*256 + row] = b2;
  }
  int eBase = (r < 4) ? r*25 : 100 + (r-4)*24;
  int eCnt  = (r < 4) ? 25 : 24;

  for (int t = 0; t < 64; ++t) {
    // 1. poll published h (tag==t, parity t&1); Xg load alongside
    if (tid < 256) {
      const unsigned long long* hp = hpub64 + ((size_t)(t & 1)*32 + b)*256 + tid;
      unsigned long long v = AT_LD(hp);
      while ((unsigned)(v >> 32) != (unsigned)t) {
        __builtin_amdgcn_s_sleep(1);
        v = AT_LD(hp);
      }
      hl_u[tid] = (unsigned)v;
    }
    float xg = (half == 1) ? Xg[((size_t)t*32 + b)*2048 + grow] : 0.f;
    __syncthreads();
    // 2. gacc = Xg + Whh[grow].h (split-K) — L2 reads hide hw-partial propagation
    float gacc = xg;
    {
      const half8_t* wr = (const half8_t*)(Whh_h + (size_t)grow*512 + half*256);
      const half8_t* hh = ((const half8_t*)(const _Float16*)hl_u) + half*32;
      for (int k8 = 0; k8 < 32; k8++) {
        half8_t w8 = wr[k8]; half8_t h8 = hh[k8];
        const half2_t* wp = (const half2_t*)&w8;
        const half2_t* hp = (const half2_t*)&h8;
        gacc = fdot2f(wp[0], hp[0], gacc);
        gacc = fdot2f(wp[1], hp[1], gacc);
        gacc = fdot2f(wp[2], hp[2], gacc);
        gacc = fdot2f(wp[3], hp[3], gacc);
      }
    }
    // 3. poll 8 hW split-K partials (contiguous 64B per d), fixed-order sum
    {
      const unsigned long long* pb = hwpub64 + (((size_t)(t & 1)*32 + b)*512 + tid)*8;
      float vals[8];
      unsigned done = 0;
      while (done != 0xFFu) {
        #pragma unroll
        for (int rr = 0; rr < 8; rr++) {
          if (!(done & (1u << rr))) {
            unsigned long long v = AT_LD(pb + rr);
            if ((unsigned)(v >> 32) == (unsigned)t) {
              union { unsigned u; float f; } c; c.u = (unsigned)v;
              vals[rr] = c.f; done |= (1u << rr);
            }
          }
        }
        if (done != 0xFFu) __builtin_amdgcn_s_sleep(1);
      }
      hwl[tid] = ((vals[0]+vals[1]) + (vals[2]+vals[3]))
               + ((vals[4]+vals[5]) + (vals[6]+vals[7]));
    }
    __syncthreads();
    // 4. REPLICATED e over all n: thread = (n = tid>>1, dhalf = tid&1)
    if (tid < 392) {
      int n = tid >> 1, dh = tid & 1;
      int base = dh << 8;
      const half8_t* fp8 = (const half8_t*)(fproj_h + ((size_t)(b*196 + n))*512 + base);
      float a = 0.f;
      for (int k8 = 0; k8 < 32; k8++) {
        half8_t f = fp8[k8];
        #pragma unroll
        for (int j = 0; j < 8; j++) {
          int k = base + k8*8 + j;
          a += vlf[k] * fast_tanh((float)f[j] + hwl[k]);
        }
      }
      a += __shfl_xor(a, 1);
      if (dh == 0) e_l[n] = a;
    }
    __syncthreads();
    // 5. softmax (block-local, replicated — bitwise identical across blocks)
    float ee = (tid < 196) ? e_l[tid] : -1e30f;
    {
      float m = ee;
      #pragma unroll
      for (int off = 32; off > 0; off >>= 1) m = fmaxf(m, __shfl_xor(m, off));
      if (lane == 0) redA[tid >> 6] = m;
    }
    __syncthreads();
    float mx = redA[0];
    #pragma unroll
    for (int i = 1; i < 8; i++) mx = fmaxf(mx, redA[i]);
    float ex = (tid < 196) ? __expf(ee - mx) : 0.f;
    {
      float s = ex;
      #pragma unroll
      for (int off = 32; off > 0; off >>= 1) s += __shfl_xor(s, off);
      if (lane == 0) redB[tid >> 6] = s;
    }
    __syncthreads();
    float tot = redB[0];
    #pragma unroll
    for (int i = 1; i < 8; i++) tot += redB[i];
    float al = ex * (1.f/tot);
    if (tid < 256) sa[tid] = al;
    if (tid >= eBase && tid < eBase + eCnt)
      abuf[(tid - eBase)*64 + t] = al;           // buffered; written after loop
    __syncthreads();
    // 6. gates: gacc += alpha . P (split-n over halves; P fully LDS-pinned)
    {
      const half2_t* P2 = (const half2_t*)P_lds;
      const float2*  sap = (const float2*)sa;
      int n2b = half*49;
      #pragma unroll 7
      for (int n2 = n2b; n2 < n2b + 49; n2++) {
        half2_t p = P2[n2*256 + row];
        float2 s2 = sap[n2];
        gacc += s2.x*(float)p[0] + s2.y*(float)p[1];
      }
      sm2[tid] = gacc;
    }
    __syncthreads();
    // 7. pointwise LSTM (c in registers); h buffered in LDS
    if (tid < 64) {
      float ig = sm2[tid]       + sm2[tid + 256];
      float fg = sm2[64 + tid]  + sm2[tid + 320];
      float gg = sm2[128 + tid] + sm2[tid + 384];
      float og = sm2[192 + tid] + sm2[tid + 448];
      float cn = fast_sig(fg)*c_reg + fast_sig(ig)*fast_tanh(gg);
      float hn = fast_sig(og)*fast_tanh(cn);
      c_reg = cn;
      hnl[tid] = hn;
      Hbuf[t*64 + tid] = (_Float16)hn;
    }
    __syncthreads();
    // 8. publish h-slice AND partial_hW (tag t+1, parity (t+1)&1); no barrier
    if (tid < 32) {
      half2_t h2; h2[0] = (_Float16)hnl[2*tid]; h2[1] = (_Float16)hnl[2*tid+1];
      union { half2_t h; unsigned u; } cv; cv.h = h2;
      AT_ST(hpub64 + ((size_t)((t + 1) & 1)*32 + b)*256 + r*32 + tid,
            ((unsigned long long)(unsigned)(t + 1) << 32) | (unsigned long long)cv.u);
    }
    {
      // partial_hW[d=tid] = Wdec[d][r*64..r*64+64) . h_slice (pinned weights)
      float a = 0.f;
      #pragma unroll
      for (int v = 0; v < 8; v++) {
        half8_t w8 = wdec_reg[v];
        #pragma unroll
        for (int j = 0; j < 8; j++) a += (float)w8[j] * hnl[v*8 + j];
      }
      union { float f; unsigned u; } cv; cv.f = a;
      AT_ST(hwpub64 + (((size_t)((t + 1) & 1)*32 + b)*512 + tid)*8 + r,
            ((unsigned long long)(unsigned)(t + 1) << 32) | (unsigned long long)cv.u);
    }
    __syncthreads();
  }

  // bulk-write buffered H and alpha
  for (int i = tid; i < 64*64; i += 512) {
    int t = i >> 6, d = i & 63;
    H_h[((size_t)t*32 + b)*512 + r*64 + d] = Hbuf[i];
  }
  for (int i = tid; i < eCnt*64; i += 512) {
    int ln = i >> 6, tt = i & 63;
    out_alpha[((size_t)b*64 + tt)*196 + eBase + ln] = abuf[ln*64 + tt];
  }
}

// ---- logits: out[b][t][:] = H[t*32+b] @ Wfc^T + bfc ----
__global__ void __launch_bounds__(512) logits_k(const _Float16* __restrict__ A,
    const _Float16* __restrict__ Bw, float* __restrict__ C,
    const float* __restrict__ bias) {
  int wave = threadIdx.x >> 6, lane = threadIdx.x & 63;
  int lr = lane & 15, quad = lane >> 4;
  int waveM = wave >> 1, waveN = wave & 1;
  int n0 = blockIdx.x*128 + waveN*64;
  const _Float16* Bp = Bw + (size_t)(n0 + lr)*512 + quad*8;
  float bv[4];
  #pragma unroll
  for (int ni = 0; ni < 4; ni++) bv[ni] = bias[n0 + ni*16 + lr];
  for (int it = 0; it < 4; ++it) {
    int m0 = (blockIdx.y*16 + it*4 + waveM)*64;
    const _Float16* Ap = A + (size_t)(m0 + lr)*512 + quad*8;
    float4_t acc[4][4];
    #pragma unroll
    for (int i = 0; i < 4; i++)
      #pragma unroll
      for (int j = 0; j < 4; j++)
        acc[i][j] = (float4_t){0.f, 0.f, 0.f, 0.f};
    for (int k0 = 0; k0 < 512; k0 += 32) {
      half8_t af[4], bf[4];
      #pragma unroll
      for (int i = 0; i < 4; i++) af[i] = *(const half8_t*)(Ap + (size_t)i*16*512 + k0);
      #pragma unroll
      for (int i = 0; i < 4; i++) bf[i] = *(const half8_t*)(Bp + (size_t)i*16*512 + k0);
      #pragma unroll
      for (int mi = 0; mi < 4; mi++)
        #pragma unroll
        for (int ni = 0; ni < 4; ni++)
          acc[mi][ni] = __builtin_amdgcn_mfma_f32_16x16x32_f16(af[mi], bf[ni], acc[mi][ni], 0, 0, 0);
    }
    #pragma unroll
    for (int mi = 0; mi < 4; mi++) {
      #pragma unroll
      for (int ni = 0; ni < 4; ni++) {
        int col = n0 + ni*16 + lr;
        #pragma unroll
        for (int r = 0; r < 4; r++) {
          int row = m0 + mi*16 + quad*4 + r;
          size_t orow = (size_t)((row & 31)*64 + (row >> 5));
          __builtin_nontemporal_store(acc[mi][ni][r] + bv[ni], C + orow*32000 + col);
        }
      }
    }
  }
}

extern "C" void kernel_launch(void* const* d_in, const int* in_sizes, int n_in,
                              void* d_out, int out_size, void* d_ws, size_t ws_size,
                              hipStream_t stream) {
  const float* imgf  = (const float*)d_in[0];
  const int*   cap   = (const int*)d_in[1];
  const float* emb   = (const float*)d_in[2];
  const float* Wh0   = (const float*)d_in[3];
  const float* bh0   = (const float*)d_in[4];
  const float* Wc0   = (const float*)d_in[5];
  const float* bc0   = (const float*)d_in[6];
  const float* Wenc  = (const float*)d_in[7];
  const float* Wdec  = (const float*)d_in[8];
  const float* v_att = (const float*)d_in[9];
  const float* W_ih  = (const float*)d_in[10];
  const float* b_ih  = (const float*)d_in[11];
  const float* W_hh  = (const float*)d_in[12];
  const float* b_hh  = (const float*)d_in[13];
  const float* Wfc   = (const float*)d_in[14];
  const float* bfc   = (const float*)d_in[15];
  float* out = (float*)d_out;
  (void)in_sizes; (void)n_in; (void)out_size; (void)ws_size;

  char* ws = (char*)d_ws;
  size_t off = 0;
  auto alloc = [&](size_t bytes) -> void* {
    void* p = ws + off;
    off += (bytes + 255) & ~(size_t)255;
    return p;
  };
  _Float16* Wenc_h  = (_Float16*)alloc((size_t)512*512*2);
  _Float16* Wdec_h  = (_Float16*)alloc((size_t)512*512*2);
  _Float16* Wih_h   = (_Float16*)alloc((size_t)2048*1024*2);
  _Float16* Whh_h   = (_Float16*)alloc((size_t)2048*512*2);
  _Float16* Wfc_h   = (_Float16*)alloc((size_t)32000*512*2);
  _Float16* imgf_h  = (_Float16*)alloc((size_t)32*196*512*2);
  _Float16* fproj_h = (_Float16*)alloc((size_t)32*196*512*2);
  _Float16* P_T     = (_Float16*)alloc((size_t)32*2048*PTLD*2);
  _Float16* X_h     = (_Float16*)alloc((size_t)64*32*512*2);
  float*    Xg      = (float*)alloc((size_t)64*32*2048*4);
  float*    bsum    = (float*)alloc((size_t)2048*4);
  float*    c_state = (float*)alloc((size_t)32*512*4);
  unsigned long long* hpub64  = (unsigned long long*)alloc((size_t)2*32*256*8);
  unsigned long long* hwpub64 = (unsigned long long*)alloc((size_t)2*32*512*8*8);
  _Float16* H_h     = (_Float16*)alloc((size_t)2048*512*2);

  // 1. all converts + gather + bias + tag invalidation (single launch)
  mega_setup_k<<<dim3(2048), dim3(256), 0, stream>>>(
      Wenc, Wenc_h, Wdec, Wdec_h, W_ih, Wih_h, W_hh, Whh_h, Wfc, Wfc_h,
      imgf, imgf_h, emb, cap, X_h, b_ih, b_hh, bsum, hpub64, hwpub64);
  // 2. h0/c0 + hW0 split-K partials (parity-0 tag-0)
  init_state_k<<<dim3(32), dim3(256), 0, stream>>>(imgf, Wh0, bh0, Wc0, bc0, Wdec,
                                                   c_state, hpub64, hwpub64);
  // 3. fproj + P_T + Xg in one launch
  setup_gemms_k<<<dim3(1476), dim3(256), 0, stream>>>(
      Wenc_h, Wih_h, imgf_h, X_h, fproj_h, P_T, Xg, bsum);

  float* out_alpha = out + (size_t)32*64*32000;
  // 4. recurrence: 32 groups x 8 blocks, single-exchange tag dataflow
  loop_k<<<dim3(256), dim3(512), 0, stream>>>(Wdec_h, Whh_h, fproj_h, P_T, Xg,
      v_att, c_state, hpub64, hwpub64, H_h, out_alpha);
  // 5. outputs = H @ Wfc^T + bfc (remapped rows)
  logits_k<<<dim3(250, 2), dim3(512), 0, stream>>>(H_h, Wfc_h, out, bfc);
}

// Round 12
// 1941.165 us; speedup vs baseline: 1.9433x; 1.9433x over previous
//
#include <hip/hip_runtime.h>
#include <cstdint>
#include <cstddef>

typedef _Float16 half2_t __attribute__((ext_vector_type(2)));
typedef _Float16 half4_t __attribute__((ext_vector_type(4)));
typedef _Float16 half8_t __attribute__((ext_vector_type(8)));
typedef float    float4_t __attribute__((ext_vector_type(4)));

#define CAPLEN 65
#define PTLD 200       // P_T / fproj_T row stride in halfs (196 used)

#define AT_LD(p)     __hip_atomic_load((p), __ATOMIC_RELAXED, __HIP_MEMORY_SCOPE_AGENT)
#define AT_ST(p, v)  __hip_atomic_store((p), (v), __ATOMIC_RELAXED, __HIP_MEMORY_SCOPE_AGENT)

#if defined(__has_builtin)
#if __has_builtin(__builtin_amdgcn_fdot2)
#define HAS_FDOT2 1
#endif
#endif

__device__ __forceinline__ float fdot2f(half2_t a, half2_t b, float c) {
#ifdef HAS_FDOT2
  return __builtin_amdgcn_fdot2(a, b, c, false);
#else
  return c + (float)a[0]*(float)b[0] + (float)a[1]*(float)b[1];
#endif
}

__device__ __forceinline__ float fast_tanh(float x) {
  float e = __expf(2.f*x);
  return 1.f - 2.f/(e + 1.f);
}
__device__ __forceinline__ float fast_sig(float x) {
  return 1.f/(1.f + __expf(-x));
}

// ---------------- mega setup: all converts + bias + gather + tag fill ----------------
// Work-item layout (quad/word granular, grid-stride):
//   [0,C1)   cvt Wenc      [C1,C2) cvt Wdec     [C2,C3) cvt W_ih
//   [C3,C4)  cvt W_hh      [C4,C5) cvt Wfc      [C5,C6) cvt imgf
//   [C6,C7)  gather emb -> X_h (fp16)
//   [C7,C8)  bias quads (bsum = b_ih + b_hh)
//   [C8,C9)  invalidate hpub64 parity-1 (parity-0 fully written by init_state_k)
//   [C9,C10) invalidate epub64 (both parities)
#define MS_C1 65536
#define MS_C2 131072
#define MS_C3 655360
#define MS_C4 917504
#define MS_C5 5013504
#define MS_C6 5816320
#define MS_C7 6078464
#define MS_C8 6078976
#define MS_C9 6087168
#define MS_C10 6218240

__device__ __forceinline__ void cvt_quad(const float* __restrict__ s,
                                         _Float16* __restrict__ d, int q) {
  float4 v = ((const float4*)s)[q];
  half4_t h;
  h[0] = (_Float16)v.x; h[1] = (_Float16)v.y; h[2] = (_Float16)v.z; h[3] = (_Float16)v.w;
  ((half4_t*)d)[q] = h;
}

__global__ void mega_setup_k(
    const float* __restrict__ Wenc, _Float16* __restrict__ Wenc_h,
    const float* __restrict__ Wdec, _Float16* __restrict__ Wdec_h,
    const float* __restrict__ Wih,  _Float16* __restrict__ Wih_h,
    const float* __restrict__ Whh,  _Float16* __restrict__ Whh_h,
    const float* __restrict__ Wfc,  _Float16* __restrict__ Wfc_h,
    const float* __restrict__ imgf, _Float16* __restrict__ imgf_h,
    const float* __restrict__ emb,  const int* __restrict__ cap,
    _Float16* __restrict__ X_h,
    const float* __restrict__ b_ih, const float* __restrict__ b_hh,
    float* __restrict__ bsum,
    unsigned long long* __restrict__ hpub64,
    unsigned long long* __restrict__ epub64) {
  int stride = gridDim.x*blockDim.x;
  for (int i = blockIdx.x*blockDim.x + threadIdx.x; i < MS_C10; i += stride) {
    if (i < MS_C1) {
      cvt_quad(Wenc, Wenc_h, i);
    } else if (i < MS_C2) {
      cvt_quad(Wdec, Wdec_h, i - MS_C1);
    } else if (i < MS_C3) {
      cvt_quad(Wih, Wih_h, i - MS_C2);
    } else if (i < MS_C4) {
      cvt_quad(Whh, Whh_h, i - MS_C3);
    } else if (i < MS_C5) {
      cvt_quad(Wfc, Wfc_h, i - MS_C4);
    } else if (i < MS_C6) {
      cvt_quad(imgf, imgf_h, i - MS_C5);
    } else if (i < MS_C7) {
      int g = i - MS_C6;               // 2048 rows x 128 quads
      int row = g >> 7, q = g & 127;
      int t = row >> 5, b = row & 31;
      int tok = cap[b*CAPLEN + t];
      float4 v = ((const float4*)(emb + (size_t)tok*512))[q];
      half4_t h;
      h[0] = (_Float16)v.x; h[1] = (_Float16)v.y; h[2] = (_Float16)v.z; h[3] = (_Float16)v.w;
      *(half4_t*)(X_h + (size_t)row*512 + q*4) = h;
    } else if (i < MS_C8) {
      int q = i - MS_C7;               // 512 quads of bias
      float4 a = ((const float4*)b_ih)[q];
      float4 b = ((const float4*)b_hh)[q];
      float4 o; o.x = a.x+b.x; o.y = a.y+b.y; o.z = a.z+b.z; o.w = a.w+b.w;
      ((float4*)bsum)[q] = o;
    } else if (i < MS_C9) {
      hpub64[8192 + (i - MS_C8)] = ~0ull;   // parity-1 h words
    } else {
      epub64[i - MS_C9] = ~0ull;            // all e words
    }
  }
}

// feat_mean -> h0 (tagged epoch-0 words in parity buffer 0), c0 (fp32)
__global__ void init_state_k(const float* __restrict__ imgf,
                             const float* __restrict__ Wh0, const float* __restrict__ bh0,
                             const float* __restrict__ Wc0, const float* __restrict__ bc0,
                             float* __restrict__ c_state,
                             unsigned long long* __restrict__ hpub64) {
  __shared__ float fm[512];
  __shared__ float hsh[512];
  int b = blockIdx.x, tid = threadIdx.x;
  for (int dI = tid; dI < 512; dI += 256) {
    float s = 0.f;
    const float* p = imgf + ((size_t)b*196)*512 + dI;
    for (int n = 0; n < 196; n++) s += p[(size_t)n*512];
    fm[dI] = s * (1.f/196.f);
  }
  __syncthreads();
  for (int dI = tid; dI < 512; dI += 256) {
    const float* wh = Wh0 + (size_t)dI*512;
    const float* wc = Wc0 + (size_t)dI*512;
    float h = bh0[dI], c = bc0[dI];
    for (int k = 0; k < 512; k++) { h += fm[k]*wh[k]; c += fm[k]*wc[k]; }
    hsh[dI] = h;
    c_state[b*512 + dI] = c;
  }
  __syncthreads();
  {
    half2_t h2; h2[0] = (_Float16)hsh[2*tid]; h2[1] = (_Float16)hsh[2*tid+1];
    union { half2_t h; unsigned u; } cv; cv.h = h2;
    hpub64[(size_t)b*256 + tid] = (unsigned long long)cv.u;   // tag 0, parity buf 0
  }
}

// ---- GEMM bodies (device functions; used by the merged setup-GEMM kernel) ----
// C[b][row][n] = sum_k A[row][k] * imgf[b][n][k]   (fp16 out, ldc=PTLD)
__device__ __forceinline__ void gemm_pt_body(const _Float16* __restrict__ A, int lda,
    const _Float16* __restrict__ Bimg, _Float16* __restrict__ Cpt, int mrows,
    int bx, int by, int bz, int tid) {
  const _Float16* B = Bimg + (size_t)bz*196*512;
  _Float16* C = Cpt + (size_t)bz*mrows*PTLD;
  int wave = tid >> 6, lane = tid & 63;
  int m0 = by*128 + (wave >> 1)*64;
  int n0 = bx*128 + (wave & 1)*64;
  int lr = lane & 15, quad = lane >> 4;
  float4_t acc[4][4];
  #pragma unroll
  for (int i = 0; i < 4; i++)
    #pragma unroll
    for (int j = 0; j < 4; j++)
      acc[i][j] = (float4_t){0.f, 0.f, 0.f, 0.f};
  const _Float16* Ap = A + (size_t)(m0 + lr)*lda + quad*8;
  const _Float16* Bp = B + (size_t)(n0 + lr)*512 + quad*8;
  for (int k0 = 0; k0 < 512; k0 += 32) {
    half8_t af[4], bf[4];
    #pragma unroll
    for (int i = 0; i < 4; i++) af[i] = *(const half8_t*)(Ap + (size_t)i*16*lda + k0);
    #pragma unroll
    for (int i = 0; i < 4; i++) bf[i] = *(const half8_t*)(Bp + (size_t)i*16*512 + k0);
    #pragma unroll
    for (int mi = 0; mi < 4; mi++)
      #pragma unroll
      for (int ni = 0; ni < 4; ni++)
        acc[mi][ni] = __builtin_amdgcn_mfma_f32_16x16x32_f16(af[mi], bf[ni], acc[mi][ni], 0, 0, 0);
  }
  #pragma unroll
  for (int mi = 0; mi < 4; mi++) {
    #pragma unroll
    for (int ni = 0; ni < 4; ni++) {
      int col = n0 + ni*16 + lr;
      if (col < PTLD) {
        #pragma unroll
        for (int r = 0; r < 4; r++) {
          int row = m0 + mi*16 + quad*4 + r;
          C[(size_t)row*PTLD + col] = (_Float16)acc[mi][ni][r];
        }
      }
    }
  }
}

// C = A * B^T + bias, fp32 out
__device__ __forceinline__ void gemm_ab0_body(const _Float16* __restrict__ A, int lda,
    const _Float16* __restrict__ B, int ldb, float* __restrict__ C, int ldc,
    const float* __restrict__ bias, int K, int bx, int by, int tid) {
  int wave = tid >> 6, lane = tid & 63;
  int m0 = by*128 + (wave >> 1)*64;
  int n0 = bx*128 + (wave & 1)*64;
  int lr = lane & 15, quad = lane >> 4;
  float4_t acc[4][4];
  #pragma unroll
  for (int i = 0; i < 4; i++)
    #pragma unroll
    for (int j = 0; j < 4; j++)
      acc[i][j] = (float4_t){0.f, 0.f, 0.f, 0.f};
  const _Float16* Ap = A + (size_t)(m0 + lr)*lda + quad*8;
  const _Float16* Bp = B + (size_t)(n0 + lr)*ldb + quad*8;
  for (int k0 = 0; k0 < K; k0 += 32) {
    half8_t af[4], bf[4];
    #pragma unroll
    for (int i = 0; i < 4; i++) af[i] = *(const half8_t*)(Ap + (size_t)i*16*lda + k0);
    #pragma unroll
    for (int i = 0; i < 4; i++) bf[i] = *(const half8_t*)(Bp + (size_t)i*16*ldb + k0);
    #pragma unroll
    for (int mi = 0; mi < 4; mi++)
      #pragma unroll
      for (int ni = 0; ni < 4; ni++)
        acc[mi][ni] = __builtin_amdgcn_mfma_f32_16x16x32_f16(af[mi], bf[ni], acc[mi][ni], 0, 0, 0);
  }
  #pragma unroll
  for (int mi = 0; mi < 4; mi++) {
    #pragma unroll
    for (int ni = 0; ni < 4; ni++) {
      int col = n0 + ni*16 + lr;
      float bv = bias[col];
      #pragma unroll
      for (int r = 0; r < 4; r++) {
        int row = m0 + mi*16 + quad*4 + r;
        C[(size_t)row*ldc + col] = acc[mi][ni][r] + bv;
      }
    }
  }
}

// merged setup GEMMs: blocks [0,256) fproj_T, [256,1280) P_T, [1280,1536) Xg
__global__ void __launch_bounds__(256) setup_gemms_k(
    const _Float16* __restrict__ Wenc_h, const _Float16* __restrict__ Wih_h,
    const _Float16* __restrict__ imgf_h, const _Float16* __restrict__ X_h,
    _Float16* __restrict__ fproj_T, _Float16* __restrict__ P_T,
    float* __restrict__ Xg, const float* __restrict__ bsum) {
  int bid = blockIdx.x, tid = threadIdx.x;
  if (bid < 256) {
    gemm_pt_body(Wenc_h, 512, imgf_h, fproj_T, 512, bid & 1, (bid >> 1) & 3, bid >> 3, tid);
  } else if (bid < 1280) {
    int l = bid - 256;
    gemm_pt_body(Wih_h + 512, 1024, imgf_h, P_T, 2048, l & 1, (l >> 1) & 15, l >> 5, tid);
  } else {
    int l = bid - 1280;
    gemm_ab0_body(X_h, 512, Wih_h, 1024, Xg, 2048, bsum, 512, l & 15, l >> 4, tid);
  }
}

// ---- persistent recurrence, BARRIER-FREE epoch-tagged dataflow (proven R9/R10) ----
__global__ void __launch_bounds__(512) loop_k(
    const _Float16* __restrict__ Wdec_h,   // [512][512]
    const _Float16* __restrict__ Whh_h,    // [2048][512]
    const _Float16* __restrict__ fproj_T,  // [32][512][PTLD]
    const _Float16* __restrict__ P_T,      // [32][2048][PTLD]
    const float*    __restrict__ Xg,       // [64*32][2048]
    const float*    __restrict__ v_att,    // [512]
    const float*    __restrict__ c_init,   // [32][512]
    unsigned long long* __restrict__ hpub64, // [2][32][256] (tag|half2)
    unsigned long long* __restrict__ epub64, // [2][32][256][8] (tag|float)
    _Float16*       __restrict__ H_h,      // [64*32][512]
    float*          __restrict__ out_alpha)// [32][64][196]
{
  __shared__ _Float16 P_lds[98*256*2];     // [n2][row][2] half2-interleaved, 100352B
  __shared__ _Float16 fp_lds[64*PTLD];     // fproj_T slice [dloc][n], 25600B
  __shared__ __align__(16) unsigned hl_u[256]; // h as packed half2
  __shared__ _Float16 Hbuf[64*64];         // own h slice per step, 8192B
  __shared__ float abuf[25*64];            // own alpha slice [ln][t], 6400B
  __shared__ float vlf[64];
  __shared__ float hwf[64];
  __shared__ float ep[2][256];
  __shared__ float redA[8];
  __shared__ float redB[8];
  __shared__ float sa[256];
  __shared__ float sm2[512];
  __shared__ float hnl[64];
  int bid = blockIdx.x, tid = threadIdx.x;
  int r = bid & 7, b = bid >> 3;
  int row = tid & 255, half = tid >> 8;
  int typ = row >> 6, dl = row & 63;
  int grow = typ*512 + r*64 + dl;          // gate row owned by (thread row)
  int lane = tid & 63;

  if (tid < 64) vlf[tid] = v_att[r*64 + tid];
  float c_reg = (tid < 64) ? c_init[b*512 + r*64 + tid] : 0.f;

  // one-time staging: P rows (tid<256) and fproj_T slice (all threads)
  if (tid < 256) {
    const _Float16* pp = P_T + ((size_t)b*2048 + grow)*PTLD;
    half2_t* P2 = (half2_t*)P_lds;
    for (int k8 = 0; k8 < 24; k8++) {
      half8_t v8 = *(const half8_t*)(pp + k8*8);
      #pragma unroll
      for (int j2 = 0; j2 < 4; j2++) {
        half2_t h2; h2[0] = v8[2*j2]; h2[1] = v8[2*j2+1];
        P2[(k8*4 + j2)*256 + row] = h2;
      }
    }
    half4_t v4 = *(const half4_t*)(pp + 192);
    half2_t a2; a2[0] = v4[0]; a2[1] = v4[1];
    half2_t b2; b2[0] = v4[2]; b2[1] = v4[3];
    P2[96*256 + row] = a2;
    P2[97*256 + row] = b2;
  } else {
    for (int i = tid - 256; i < 64*25; i += 256) {
      int d = i/25, c = i - d*25;
      *(half8_t*)(fp_lds + d*PTLD + c*8) =
        *(const half8_t*)(fproj_T + ((size_t)(b*512 + r*64 + d))*PTLD + c*8);
    }
  }
  int eBase = (r < 4) ? r*25 : 100 + (r-4)*24;
  int eCnt  = (r < 4) ? 25 : 24;

  for (int t = 0; t < 64; ++t) {
    // 1. poll published h (tag==t, parity t&1); Xg load on the other half
    if (tid < 256) {
      const unsigned long long* hp = hpub64 + ((size_t)(t & 1)*32 + b)*256 + tid;
      unsigned long long v = AT_LD(hp);
      while ((unsigned)(v >> 32) != (unsigned)t) {
        __builtin_amdgcn_s_sleep(1);
        v = AT_LD(hp);
      }
      hl_u[tid] = (unsigned)v;
    }
    float xg = (half == 1) ? Xg[((size_t)t*32 + b)*2048 + grow] : 0.f;
    __syncthreads();
    // 2. hW own slice: thread = dim*8 + s, shfl-reduce over s
    {
      int dim = tid >> 3, s = tid & 7;
      const half8_t* wr = (const half8_t*)(Wdec_h + (size_t)(r*64 + dim)*512 + s*64);
      const half8_t* hh = ((const half8_t*)(const _Float16*)hl_u) + s*8;
      float a = 0.f;
      #pragma unroll
      for (int k8 = 0; k8 < 8; k8++) {
        half8_t w8 = wr[k8]; half8_t h8 = hh[k8];
        const half2_t* wp = (const half2_t*)&w8;
        const half2_t* hp = (const half2_t*)&h8;
        a = fdot2f(wp[0], hp[0], a);
        a = fdot2f(wp[1], hp[1], a);
        a = fdot2f(wp[2], hp[2], a);
        a = fdot2f(wp[3], hp[3], a);
      }
      a += __shfl_xor(a, 1);
      a += __shfl_xor(a, 2);
      a += __shfl_xor(a, 4);
      if (s == 0) hwf[dim] = a;
    }
    __syncthreads();
    // 3. e-partials over own 64 dims: thread = (n=row, dgroup=half)
    {
      float a = 0.f;
      if (row < 196) {
        #pragma unroll 8
        for (int j = 0; j < 32; j++) {
          int dd = half*32 + j;
          a += vlf[dd] * fast_tanh((float)fp_lds[dd*PTLD + row] + hwf[dd]);
        }
      }
      ep[half][row] = a;
    }
    __syncthreads();
    // 4. publish tagged e partial (parity t&1)
    if (tid < 196) {
      union { float f; unsigned u; } c; c.f = ep[0][tid] + ep[1][tid];
      AT_ST(epub64 + (((size_t)(t & 1)*32 + b)*256 + tid)*8 + r,
            ((unsigned long long)(unsigned)t << 32) | (unsigned long long)c.u);
    }
    // 5. gacc = Xg + Whh[grow].h (split-K) — overlaps e propagation to peers
    float gacc = xg;
    {
      const half8_t* wr = (const half8_t*)(Whh_h + (size_t)grow*512 + half*256);
      const half8_t* hh = ((const half8_t*)(const _Float16*)hl_u) + half*32;
      for (int k8 = 0; k8 < 32; k8++) {
        half8_t w8 = wr[k8]; half8_t h8 = hh[k8];
        const half2_t* wp = (const half2_t*)&w8;
        const half2_t* hp = (const half2_t*)&h8;
        gacc = fdot2f(wp[0], hp[0], gacc);
        gacc = fdot2f(wp[1], hp[1], gacc);
        gacc = fdot2f(wp[2], hp[2], gacc);
        gacc = fdot2f(wp[3], hp[3], gacc);
      }
    }
    // 6. poll all 8 e-partials (contiguous 64B per n), fixed-order sum
    float ee = -1e30f;
    if (tid < 196) {
      const unsigned long long* pb = epub64 + (((size_t)(t & 1)*32 + b)*256 + tid)*8;
      float vals[8];
      unsigned done = 0;
      while (done != 0xFFu) {
        #pragma unroll
        for (int rr = 0; rr < 8; rr++) {
          if (!(done & (1u << rr))) {
            unsigned long long v = AT_LD(pb + rr);
            if ((unsigned)(v >> 32) == (unsigned)t) {
              union { unsigned u; float f; } c; c.u = (unsigned)v;
              vals[rr] = c.f; done |= (1u << rr);
            }
          }
        }
        if (done != 0xFFu) __builtin_amdgcn_s_sleep(1);
      }
      ee = ((vals[0]+vals[1]) + (vals[2]+vals[3])) + ((vals[4]+vals[5]) + (vals[6]+vals[7]));
    }
    // 7. softmax (replicated, block-local reduce)
    {
      float m = ee;
      #pragma unroll
      for (int off = 32; off > 0; off >>= 1) m = fmaxf(m, __shfl_xor(m, off));
      if (lane == 0) redA[tid >> 6] = m;
    }
    __syncthreads();
    float mx = redA[0];
    #pragma unroll
    for (int i = 1; i < 8; i++) mx = fmaxf(mx, redA[i]);
    float ex = (tid < 196) ? __expf(ee - mx) : 0.f;
    {
      float s = ex;
      #pragma unroll
      for (int off = 32; off > 0; off >>= 1) s += __shfl_xor(s, off);
      if (lane == 0) redB[tid >> 6] = s;
    }
    __syncthreads();
    float tot = redB[0];
    #pragma unroll
    for (int i = 1; i < 8; i++) tot += redB[i];
    float al = ex * (1.f/tot);
    if (tid < 256) sa[tid] = al;
    if (tid >= eBase && tid < eBase + eCnt)
      abuf[(tid - eBase)*64 + t] = al;           // buffered; written after loop
    __syncthreads();
    // 8. gates: gacc += alpha . P (split-n over halves; P fully LDS-pinned)
    {
      const half2_t* P2 = (const half2_t*)P_lds;
      const float2*  sap = (const float2*)sa;
      int n2b = half*49;
      #pragma unroll 7
      for (int n2 = n2b; n2 < n2b + 49; n2++) {
        half2_t p = P2[n2*256 + row];
        float2 s2 = sap[n2];
        gacc += s2.x*(float)p[0] + s2.y*(float)p[1];
      }
      sm2[tid] = gacc;
    }
    __syncthreads();
    // 9. pointwise LSTM (c in registers); h buffered in LDS
    if (tid < 64) {
      float ig = sm2[tid]       + sm2[tid + 256];
      float fg = sm2[64 + tid]  + sm2[tid + 320];
      float gg = sm2[128 + tid] + sm2[tid + 384];
      float og = sm2[192 + tid] + sm2[tid + 448];
      float cn = fast_sig(fg)*c_reg + fast_sig(ig)*fast_tanh(gg);
      float hn = fast_sig(og)*fast_tanh(cn);
      c_reg = cn;
      hnl[tid] = hn;
      Hbuf[t*64 + tid] = (_Float16)hn;
    }
    __syncthreads();
    // 10. publish tagged h slice (tag t+1, parity (t+1)&1); no barrier
    if (tid < 32) {
      half2_t h2; h2[0] = (_Float16)hnl[2*tid]; h2[1] = (_Float16)hnl[2*tid+1];
      union { half2_t h; unsigned u; } cv; cv.h = h2;
      AT_ST(hpub64 + ((size_t)((t + 1) & 1)*32 + b)*256 + r*32 + tid,
            ((unsigned long long)(unsigned)(t + 1) << 32) | (unsigned long long)cv.u);
    }
    __syncthreads();
  }

  // bulk-write buffered H and alpha
  for (int i = tid; i < 64*64; i += 512) {
    int t = i >> 6, d = i & 63;
    H_h[((size_t)t*32 + b)*512 + r*64 + d] = Hbuf[i];
  }
  for (int i = tid; i < eCnt*64; i += 512) {
    int ln = i >> 6, tt = i & 63;
    out_alpha[((size_t)b*64 + tt)*196 + eBase + ln] = abuf[ln*64 + tt];
  }
}

// ---- logits: out[b][t][:] = H[t*32+b] @ Wfc^T + bfc ----
__global__ void __launch_bounds__(512) logits_k(const _Float16* __restrict__ A,
    const _Float16* __restrict__ Bw, float* __restrict__ C,
    const float* __restrict__ bias) {
  int wave = threadIdx.x >> 6, lane = threadIdx.x & 63;
  int lr = lane & 15, quad = lane >> 4;
  int waveM = wave >> 1, waveN = wave & 1;
  int n0 = blockIdx.x*128 + waveN*64;
  const _Float16* Bp = Bw + (size_t)(n0 + lr)*512 + quad*8;
  float bv[4];
  #pragma unroll
  for (int ni = 0; ni < 4; ni++) bv[ni] = bias[n0 + ni*16 + lr];
  for (int it = 0; it < 4; ++it) {
    int m0 = (blockIdx.y*16 + it*4 + waveM)*64;
    const _Float16* Ap = A + (size_t)(m0 + lr)*512 + quad*8;
    float4_t acc[4][4];
    #pragma unroll
    for (int i = 0; i < 4; i++)
      #pragma unroll
      for (int j = 0; j < 4; j++)
        acc[i][j] = (float4_t){0.f, 0.f, 0.f, 0.f};
    for (int k0 = 0; k0 < 512; k0 += 32) {
      half8_t af[4], bf[4];
      #pragma unroll
      for (int i = 0; i < 4; i++) af[i] = *(const half8_t*)(Ap + (size_t)i*16*512 + k0);
      #pragma unroll
      for (int i = 0; i < 4; i++) bf[i] = *(const half8_t*)(Bp + (size_t)i*16*512 + k0);
      #pragma unroll
      for (int mi = 0; mi < 4; mi++)
        #pragma unroll
        for (int ni = 0; ni < 4; ni++)
          acc[mi][ni] = __builtin_amdgcn_mfma_f32_16x16x32_f16(af[mi], bf[ni], acc[mi][ni], 0, 0, 0);
    }
    #pragma unroll
    for (int mi = 0; mi < 4; mi++) {
      #pragma unroll
      for (int ni = 0; ni < 4; ni++) {
        int col = n0 + ni*16 + lr;
        #pragma unroll
        for (int r = 0; r < 4; r++) {
          int row = m0 + mi*16 + quad*4 + r;
          size_t orow = (size_t)((row & 31)*64 + (row >> 5));
          __builtin_nontemporal_store(acc[mi][ni][r] + bv[ni], C + orow*32000 + col);
        }
      }
    }
  }
}

extern "C" void kernel_launch(void* const* d_in, const int* in_sizes, int n_in,
                              void* d_out, int out_size, void* d_ws, size_t ws_size,
                              hipStream_t stream) {
  const float* imgf  = (const float*)d_in[0];
  const int*   cap   = (const int*)d_in[1];
  const float* emb   = (const float*)d_in[2];
  const float* Wh0   = (const float*)d_in[3];
  const float* bh0   = (const float*)d_in[4];
  const float* Wc0   = (const float*)d_in[5];
  const float* bc0   = (const float*)d_in[6];
  const float* Wenc  = (const float*)d_in[7];
  const float* Wdec  = (const float*)d_in[8];
  const float* v_att = (const float*)d_in[9];
  const float* W_ih  = (const float*)d_in[10];
  const float* b_ih  = (const float*)d_in[11];
  const float* W_hh  = (const float*)d_in[12];
  const float* b_hh  = (const float*)d_in[13];
  const float* Wfc   = (const float*)d_in[14];
  const float* bfc   = (const float*)d_in[15];
  float* out = (float*)d_out;
  (void)in_sizes; (void)n_in; (void)out_size; (void)ws_size;

  char* ws = (char*)d_ws;
  size_t off = 0;
  auto alloc = [&](size_t bytes) -> void* {
    void* p = ws + off;
    off += (bytes + 255) & ~(size_t)255;
    return p;
  };
  _Float16* Wenc_h  = (_Float16*)alloc((size_t)512*512*2);
  _Float16* Wdec_h  = (_Float16*)alloc((size_t)512*512*2);
  _Float16* Wih_h   = (_Float16*)alloc((size_t)2048*1024*2);
  _Float16* Whh_h   = (_Float16*)alloc((size_t)2048*512*2);
  _Float16* Wfc_h   = (_Float16*)alloc((size_t)32000*512*2);
  _Float16* imgf_h  = (_Float16*)alloc((size_t)32*196*512*2);
  _Float16* fproj_T = (_Float16*)alloc((size_t)32*512*PTLD*2);
  _Float16* P_T     = (_Float16*)alloc((size_t)32*2048*PTLD*2);
  _Float16* X_h     = (_Float16*)alloc((size_t)64*32*512*2);
  float*    Xg      = (float*)alloc((size_t)64*32*2048*4);
  float*    bsum    = (float*)alloc((size_t)2048*4);
  float*    c_state = (float*)alloc((size_t)32*512*4);
  unsigned long long* hpub64 = (unsigned long long*)alloc((size_t)2*32*256*8);
  unsigned long long* epub64 = (unsigned long long*)alloc((size_t)2*32*256*8*8);
  _Float16* H_h     = (_Float16*)alloc((size_t)2048*512*2);

  // 1. all converts + gather + bias + tag invalidation (single launch)
  mega_setup_k<<<dim3(2048), dim3(256), 0, stream>>>(
      Wenc, Wenc_h, Wdec, Wdec_h, W_ih, Wih_h, W_hh, Whh_h, Wfc, Wfc_h,
      imgf, imgf_h, emb, cap, X_h, b_ih, b_hh, bsum, hpub64, epub64);
  // 2. h0/c0 (publishes parity-0 tag-0 h words; disjoint from mega's fills)
  init_state_k<<<dim3(32), dim3(256), 0, stream>>>(imgf, Wh0, bh0, Wc0, bc0, c_state, hpub64);
  // 3. fproj_T + P_T + Xg in one launch
  setup_gemms_k<<<dim3(1536), dim3(256), 0, stream>>>(
      Wenc_h, Wih_h, imgf_h, X_h, fproj_T, P_T, Xg, bsum);

  float* out_alpha = out + (size_t)32*64*32000;
  // 4. all 64 recurrence steps: 32 groups x 8 blocks, 512 thr, tag dataflow
  loop_k<<<dim3(256), dim3(512), 0, stream>>>(Wdec_h, Whh_h, fproj_T, P_T, Xg,
      v_att, c_state, hpub64, epub64, H_h, out_alpha);
  // 5. outputs = H @ Wfc^T + bfc (remapped rows)
  logits_k<<<dim3(250, 2), dim3(512), 0, stream>>>(H_h, Wfc_h, out, bfc);
}

// Round 13
// 1930.414 us; speedup vs baseline: 1.9541x; 1.0056x over previous
//
#include <hip/hip_runtime.h>
#include <cstdint>
#include <cstddef>

typedef _Float16 half2_t __attribute__((ext_vector_type(2)));
typedef _Float16 half4_t __attribute__((ext_vector_type(4)));
typedef _Float16 half8_t __attribute__((ext_vector_type(8)));
typedef float    float4_t __attribute__((ext_vector_type(4)));

#define CAPLEN 65
#define PTLD 200       // P_T / fproj_T row stride in halfs (196 used)

#define AT_LD(p)     __hip_atomic_load((p), __ATOMIC_RELAXED, __HIP_MEMORY_SCOPE_AGENT)
#define AT_ST(p, v)  __hip_atomic_store((p), (v), __ATOMIC_RELAXED, __HIP_MEMORY_SCOPE_AGENT)

#if defined(__has_builtin)
#if __has_builtin(__builtin_amdgcn_fdot2)
#define HAS_FDOT2 1
#endif
#endif

__device__ __forceinline__ float fdot2f(half2_t a, half2_t b, float c) {
#ifdef HAS_FDOT2
  return __builtin_amdgcn_fdot2(a, b, c, false);
#else
  return c + (float)a[0]*(float)b[0] + (float)a[1]*(float)b[1];
#endif
}

__device__ __forceinline__ float fast_tanh(float x) {
  float e = __expf(2.f*x);
  return 1.f - 2.f/(e + 1.f);
}
__device__ __forceinline__ float fast_sig(float x) {
  return 1.f/(1.f + __expf(-x));
}

// ---------------- mega setup: all converts + bias + gather + tag fill ----------------
// Work-item layout (quad/word granular, grid-stride):
//   [0,C1)   cvt Wenc      [C1,C2) cvt Wdec     [C2,C3) cvt W_ih
//   [C3,C4)  cvt W_hh      [C4,C5) cvt Wfc      [C5,C6) cvt imgf
//   [C6,C7)  gather emb -> X_h (fp16)
//   [C7,C8)  bias quads (bsum = b_ih + b_hh)
//   [C8,C9)  invalidate hpub64 parity-1 (parity-0 fully written by init_state_k)
//   [C9,C10) invalidate epub64 (both parities)
#define MS_C1 65536
#define MS_C2 131072
#define MS_C3 655360
#define MS_C4 917504
#define MS_C5 5013504
#define MS_C6 5816320
#define MS_C7 6078464
#define MS_C8 6078976
#define MS_C9 6087168
#define MS_C10 6218240

__device__ __forceinline__ void cvt_quad(const float* __restrict__ s,
                                         _Float16* __restrict__ d, int q) {
  float4 v = ((const float4*)s)[q];
  half4_t h;
  h[0] = (_Float16)v.x; h[1] = (_Float16)v.y; h[2] = (_Float16)v.z; h[3] = (_Float16)v.w;
  ((half4_t*)d)[q] = h;
}

__global__ void mega_setup_k(
    const float* __restrict__ Wenc, _Float16* __restrict__ Wenc_h,
    const float* __restrict__ Wdec, _Float16* __restrict__ Wdec_h,
    const float* __restrict__ Wih,  _Float16* __restrict__ Wih_h,
    const float* __restrict__ Whh,  _Float16* __restrict__ Whh_h,
    const float* __restrict__ Wfc,  _Float16* __restrict__ Wfc_h,
    const float* __restrict__ imgf, _Float16* __restrict__ imgf_h,
    const float* __restrict__ emb,  const int* __restrict__ cap,
    _Float16* __restrict__ X_h,
    const float* __restrict__ b_ih, const float* __restrict__ b_hh,
    float* __restrict__ bsum,
    unsigned long long* __restrict__ hpub64,
    unsigned long long* __restrict__ epub64) {
  int stride = gridDim.x*blockDim.x;
  for (int i = blockIdx.x*blockDim.x + threadIdx.x; i < MS_C10; i += stride) {
    if (i < MS_C1) {
      cvt_quad(Wenc, Wenc_h, i);
    } else if (i < MS_C2) {
      cvt_quad(Wdec, Wdec_h, i - MS_C1);
    } else if (i < MS_C3) {
      cvt_quad(Wih, Wih_h, i - MS_C2);
    } else if (i < MS_C4) {
      cvt_quad(Whh, Whh_h, i - MS_C3);
    } else if (i < MS_C5) {
      cvt_quad(Wfc, Wfc_h, i - MS_C4);
    } else if (i < MS_C6) {
      cvt_quad(imgf, imgf_h, i - MS_C5);
    } else if (i < MS_C7) {
      int g = i - MS_C6;               // 2048 rows x 128 quads
      int row = g >> 7, q = g & 127;
      int t = row >> 5, b = row & 31;
      int tok = cap[b*CAPLEN + t];
      float4 v = ((const float4*)(emb + (size_t)tok*512))[q];
      half4_t h;
      h[0] = (_Float16)v.x; h[1] = (_Float16)v.y; h[2] = (_Float16)v.z; h[3] = (_Float16)v.w;
      *(half4_t*)(X_h + (size_t)row*512 + q*4) = h;
    } else if (i < MS_C8) {
      int q = i - MS_C7;               // 512 quads of bias
      float4 a = ((const float4*)b_ih)[q];
      float4 b = ((const float4*)b_hh)[q];
      float4 o; o.x = a.x+b.x; o.y = a.y+b.y; o.z = a.z+b.z; o.w = a.w+b.w;
      ((float4*)bsum)[q] = o;
    } else if (i < MS_C9) {
      hpub64[8192 + (i - MS_C8)] = ~0ull;   // parity-1 h words
    } else {
      epub64[i - MS_C9] = ~0ull;            // all e words
    }
  }
}

// feat_mean -> h0 (tagged epoch-0 words in parity buffer 0), c0 (fp32)
__global__ void init_state_k(const float* __restrict__ imgf,
                             const float* __restrict__ Wh0, const float* __restrict__ bh0,
                             const float* __restrict__ Wc0, const float* __restrict__ bc0,
                             float* __restrict__ c_state,
                             unsigned long long* __restrict__ hpub64) {
  __shared__ float fm[512];
  __shared__ float hsh[512];
  int b = blockIdx.x, tid = threadIdx.x;
  for (int dI = tid; dI < 512; dI += 256) {
    float s = 0.f;
    const float* p = imgf + ((size_t)b*196)*512 + dI;
    for (int n = 0; n < 196; n++) s += p[(size_t)n*512];
    fm[dI] = s * (1.f/196.f);
  }
  __syncthreads();
  for (int dI = tid; dI < 512; dI += 256) {
    const float* wh = Wh0 + (size_t)dI*512;
    const float* wc = Wc0 + (size_t)dI*512;
    float h = bh0[dI], c = bc0[dI];
    for (int k = 0; k < 512; k++) { h += fm[k]*wh[k]; c += fm[k]*wc[k]; }
    hsh[dI] = h;
    c_state[b*512 + dI] = c;
  }
  __syncthreads();
  {
    half2_t h2; h2[0] = (_Float16)hsh[2*tid]; h2[1] = (_Float16)hsh[2*tid+1];
    union { half2_t h; unsigned u; } cv; cv.h = h2;
    hpub64[(size_t)b*256 + tid] = (unsigned long long)cv.u;   // tag 0, parity buf 0
  }
}

// ---- GEMM bodies (device functions; used by the merged setup-GEMM kernel) ----
// C[b][row][n] = sum_k A[row][k] * imgf[b][n][k]   (fp16 out, ldc=PTLD)
__device__ __forceinline__ void gemm_pt_body(const _Float16* __restrict__ A, int lda,
    const _Float16* __restrict__ Bimg, _Float16* __restrict__ Cpt, int mrows,
    int bx, int by, int bz, int tid) {
  const _Float16* B = Bimg + (size_t)bz*196*512;
  _Float16* C = Cpt + (size_t)bz*mrows*PTLD;
  int wave = tid >> 6, lane = tid & 63;
  int m0 = by*128 + (wave >> 1)*64;
  int n0 = bx*128 + (wave & 1)*64;
  int lr = lane & 15, quad = lane >> 4;
  float4_t acc[4][4];
  #pragma unroll
  for (int i = 0; i < 4; i++)
    #pragma unroll
    for (int j = 0; j < 4; j++)
      acc[i][j] = (float4_t){0.f, 0.f, 0.f, 0.f};
  const _Float16* Ap = A + (size_t)(m0 + lr)*lda + quad*8;
  const _Float16* Bp = B + (size_t)(n0 + lr)*512 + quad*8;
  for (int k0 = 0; k0 < 512; k0 += 32) {
    half8_t af[4], bf[4];
    #pragma unroll
    for (int i = 0; i < 4; i++) af[i] = *(const half8_t*)(Ap + (size_t)i*16*lda + k0);
    #pragma unroll
    for (int i = 0; i < 4; i++) bf[i] = *(const half8_t*)(Bp + (size_t)i*16*512 + k0);
    #pragma unroll
    for (int mi = 0; mi < 4; mi++)
      #pragma unroll
      for (int ni = 0; ni < 4; ni++)
        acc[mi][ni] = __builtin_amdgcn_mfma_f32_16x16x32_f16(af[mi], bf[ni], acc[mi][ni], 0, 0, 0);
  }
  #pragma unroll
  for (int mi = 0; mi < 4; mi++) {
    #pragma unroll
    for (int ni = 0; ni < 4; ni++) {
      int col = n0 + ni*16 + lr;
      if (col < PTLD) {
        #pragma unroll
        for (int r = 0; r < 4; r++) {
          int row = m0 + mi*16 + quad*4 + r;
          C[(size_t)row*PTLD + col] = (_Float16)acc[mi][ni][r];
        }
      }
    }
  }
}

// C = A * B^T + bias, fp32 out
__device__ __forceinline__ void gemm_ab0_body(const _Float16* __restrict__ A, int lda,
    const _Float16* __restrict__ B, int ldb, float* __restrict__ C, int ldc,
    const float* __restrict__ bias, int K, int bx, int by, int tid) {
  int wave = tid >> 6, lane = tid & 63;
  int m0 = by*128 + (wave >> 1)*64;
  int n0 = bx*128 + (wave & 1)*64;
  int lr = lane & 15, quad = lane >> 4;
  float4_t acc[4][4];
  #pragma unroll
  for (int i = 0; i < 4; i++)
    #pragma unroll
    for (int j = 0; j < 4; j++)
      acc[i][j] = (float4_t){0.f, 0.f, 0.f, 0.f};
  const _Float16* Ap = A + (size_t)(m0 + lr)*lda + quad*8;
  const _Float16* Bp = B + (size_t)(n0 + lr)*ldb + quad*8;
  for (int k0 = 0; k0 < K; k0 += 32) {
    half8_t af[4], bf[4];
    #pragma unroll
    for (int i = 0; i < 4; i++) af[i] = *(const half8_t*)(Ap + (size_t)i*16*lda + k0);
    #pragma unroll
    for (int i = 0; i < 4; i++) bf[i] = *(const half8_t*)(Bp + (size_t)i*16*ldb + k0);
    #pragma unroll
    for (int mi = 0; mi < 4; mi++)
      #pragma unroll
      for (int ni = 0; ni < 4; ni++)
        acc[mi][ni] = __builtin_amdgcn_mfma_f32_16x16x32_f16(af[mi], bf[ni], acc[mi][ni], 0, 0, 0);
  }
  #pragma unroll
  for (int mi = 0; mi < 4; mi++) {
    #pragma unroll
    for (int ni = 0; ni < 4; ni++) {
      int col = n0 + ni*16 + lr;
      float bv = bias[col];
      #pragma unroll
      for (int r = 0; r < 4; r++) {
        int row = m0 + mi*16 + quad*4 + r;
        C[(size_t)row*ldc + col] = acc[mi][ni][r] + bv;
      }
    }
  }
}

// merged setup GEMMs: blocks [0,256) fproj_T, [256,1280) P_T, [1280,1536) Xg
__global__ void __launch_bounds__(256) setup_gemms_k(
    const _Float16* __restrict__ Wenc_h, const _Float16* __restrict__ Wih_h,
    const _Float16* __restrict__ imgf_h, const _Float16* __restrict__ X_h,
    _Float16* __restrict__ fproj_T, _Float16* __restrict__ P_T,
    float* __restrict__ Xg, const float* __restrict__ bsum) {
  int bid = blockIdx.x, tid = threadIdx.x;
  if (bid < 256) {
    gemm_pt_body(Wenc_h, 512, imgf_h, fproj_T, 512, bid & 1, (bid >> 1) & 3, bid >> 3, tid);
  } else if (bid < 1280) {
    int l = bid - 256;
    gemm_pt_body(Wih_h + 512, 1024, imgf_h, P_T, 2048, l & 1, (l >> 1) & 15, l >> 5, tid);
  } else {
    int l = bid - 1280;
    gemm_ab0_body(X_h, 512, Wih_h, 1024, Xg, 2048, bsum, 512, l & 15, l >> 4, tid);
  }
}

// ---- persistent recurrence, BARRIER-FREE epoch-tagged dataflow (proven R9/R10) ----
__global__ void __launch_bounds__(512) loop_k(
    const _Float16* __restrict__ Wdec_h,   // [512][512]
    const _Float16* __restrict__ Whh_h,    // [2048][512]
    const _Float16* __restrict__ fproj_T,  // [32][512][PTLD]
    const _Float16* __restrict__ P_T,      // [32][2048][PTLD]
    const float*    __restrict__ Xg,       // [64*32][2048]
    const float*    __restrict__ v_att,    // [512]
    const float*    __restrict__ c_init,   // [32][512]
    unsigned long long* __restrict__ hpub64, // [2][32][256] (tag|half2)
    unsigned long long* __restrict__ epub64, // [2][32][256][8] (tag|float)
    _Float16*       __restrict__ H_h,      // [64*32][512]
    float*          __restrict__ out_alpha)// [32][64][196]
{
  __shared__ _Float16 P_lds[98*256*2];     // [n2][row][2] half2-interleaved, 100352B
  __shared__ _Float16 fp_lds[64*PTLD];     // fproj_T slice [dloc][n], 25600B
  __shared__ __align__(16) unsigned hl_u[256]; // h as packed half2
  __shared__ _Float16 Hbuf[64*64];         // own h slice per step, 8192B
  __shared__ float abuf[25*64];            // own alpha slice [ln][t], 6400B
  __shared__ float vlf[64];
  __shared__ float hwf[64];
  __shared__ float ep[2][256];
  __shared__ float redA[8];
  __shared__ float redB[8];
  __shared__ float sa[256];
  __shared__ float sm2[512];
  __shared__ float hnl[64];
  int bid = blockIdx.x, tid = threadIdx.x;
  int r = bid & 7, b = bid >> 3;
  int row = tid & 255, half = tid >> 8;
  int typ = row >> 6, dl = row & 63;
  int grow = typ*512 + r*64 + dl;          // gate row owned by (thread row)
  int lane = tid & 63;

  if (tid < 64) vlf[tid] = v_att[r*64 + tid];
  float c_reg = (tid < 64) ? c_init[b*512 + r*64 + tid] : 0.f;

  // one-time staging: P rows (tid<256) and fproj_T slice (all threads)
  if (tid < 256) {
    const _Float16* pp = P_T + ((size_t)b*2048 + grow)*PTLD;
    half2_t* P2 = (half2_t*)P_lds;
    for (int k8 = 0; k8 < 24; k8++) {
      half8_t v8 = *(const half8_t*)(pp + k8*8);
      #pragma unroll
      for (int j2 = 0; j2 < 4; j2++) {
        half2_t h2; h2[0] = v8[2*j2]; h2[1] = v8[2*j2+1];
        P2[(k8*4 + j2)*256 + row] = h2;
      }
    }
    half4_t v4 = *(const half4_t*)(pp + 192);
    half2_t a2; a2[0] = v4[0]; a2[1] = v4[1];
    half2_t b2; b2[0] = v4[2]; b2[1] = v4[3];
    P2[96*256 + row] = a2;
    P2[97*256 + row] = b2;
  } else {
    for (int i = tid - 256; i < 64*25; i += 256) {
      int d = i/25, c = i - d*25;
      *(half8_t*)(fp_lds + d*PTLD + c*8) =
        *(const half8_t*)(fproj_T + ((size_t)(b*512 + r*64 + d))*PTLD + c*8);
    }
  }
  int eBase = (r < 4) ? r*25 : 100 + (r-4)*24;
  int eCnt  = (r < 4) ? 25 : 24;

  for (int t = 0; t < 64; ++t) {
    // 1. poll published h (tag==t, parity t&1); Xg load on the other half
    if (tid < 256) {
      const unsigned long long* hp = hpub64 + ((size_t)(t & 1)*32 + b)*256 + tid;
      unsigned long long v = AT_LD(hp);
      while ((unsigned)(v >> 32) != (unsigned)t) {
        __builtin_amdgcn_s_sleep(1);
        v = AT_LD(hp);
      }
      hl_u[tid] = (unsigned)v;
    }
    float xg = (half == 1) ? Xg[((size_t)t*32 + b)*2048 + grow] : 0.f;
    __syncthreads();
    // 2. hW own slice: thread = dim*8 + s, shfl-reduce over s
    {
      int dim = tid >> 3, s = tid & 7;
      const half8_t* wr = (const half8_t*)(Wdec_h + (size_t)(r*64 + dim)*512 + s*64);
      const half8_t* hh = ((const half8_t*)(const _Float16*)hl_u) + s*8;
      float a = 0.f;
      #pragma unroll
      for (int k8 = 0; k8 < 8; k8++) {
        half8_t w8 = wr[k8]; half8_t h8 = hh[k8];
        const half2_t* wp = (const half2_t*)&w8;
        const half2_t* hp = (const half2_t*)&h8;
        a = fdot2f(wp[0], hp[0], a);
        a = fdot2f(wp[1], hp[1], a);
        a = fdot2f(wp[2], hp[2], a);
        a = fdot2f(wp[3], hp[3], a);
      }
      a += __shfl_xor(a, 1);
      a += __shfl_xor(a, 2);
      a += __shfl_xor(a, 4);
      if (s == 0) hwf[dim] = a;
    }
    __syncthreads();
    // 3. e-partials over own 64 dims: thread = (n=row, dgroup=half)
    {
      float a = 0.f;
      if (row < 196) {
        #pragma unroll 8
        for (int j = 0; j < 32; j++) {
          int dd = half*32 + j;
          a += vlf[dd] * fast_tanh((float)fp_lds[dd*PTLD + row] + hwf[dd]);
        }
      }
      ep[half][row] = a;
    }
    __syncthreads();
    // 4. publish tagged e partial (parity t&1)
    if (tid < 196) {
      union { float f; unsigned u; } c; c.f = ep[0][tid] + ep[1][tid];
      AT_ST(epub64 + (((size_t)(t & 1)*32 + b)*256 + tid)*8 + r,
            ((unsigned long long)(unsigned)t << 32) | (unsigned long long)c.u);
    }
    // 5. gacc = Xg + Whh[grow].h (split-K) — overlaps e propagation to peers
    float gacc = xg;
    {
      const half8_t* wr = (const half8_t*)(Whh_h + (size_t)grow*512 + half*256);
      const half8_t* hh = ((const half8_t*)(const _Float16*)hl_u) + half*32;
      for (int k8 = 0; k8 < 32; k8++) {
        half8_t w8 = wr[k8]; half8_t h8 = hh[k8];
        const half2_t* wp = (const half2_t*)&w8;
        const half2_t* hp = (const half2_t*)&h8;
        gacc = fdot2f(wp[0], hp[0], gacc);
        gacc = fdot2f(wp[1], hp[1], gacc);
        gacc = fdot2f(wp[2], hp[2], gacc);
        gacc = fdot2f(wp[3], hp[3], gacc);
      }
    }
    // 6. poll all 8 e-partials (contiguous 64B per n), fixed-order sum
    float ee = -1e30f;
    if (tid < 196) {
      const unsigned long long* pb = epub64 + (((size_t)(t & 1)*32 + b)*256 + tid)*8;
      float vals[8];
      unsigned done = 0;
      while (done != 0xFFu) {
        #pragma unroll
        for (int rr = 0; rr < 8; rr++) {
          if (!(done & (1u << rr))) {
            unsigned long long v = AT_LD(pb + rr);
            if ((unsigned)(v >> 32) == (unsigned)t) {
              union { unsigned u; float f; } c; c.u = (unsigned)v;
              vals[rr] = c.f; done |= (1u << rr);
            }
          }
        }
        if (done != 0xFFu) __builtin_amdgcn_s_sleep(1);
      }
      ee = ((vals[0]+vals[1]) + (vals[2]+vals[3])) + ((vals[4]+vals[5]) + (vals[6]+vals[7]));
    }
    // 7. softmax (replicated, block-local reduce)
    {
      float m = ee;
      #pragma unroll
      for (int off = 32; off > 0; off >>= 1) m = fmaxf(m, __shfl_xor(m, off));
      if (lane == 0) redA[tid >> 6] = m;
    }
    __syncthreads();
    float mx = redA[0];
    #pragma unroll
    for (int i = 1; i < 8; i++) mx = fmaxf(mx, redA[i]);
    float ex = (tid < 196) ? __expf(ee - mx) : 0.f;
    {
      float s = ex;
      #pragma unroll
      for (int off = 32; off > 0; off >>= 1) s += __shfl_xor(s, off);
      if (lane == 0) redB[tid >> 6] = s;
    }
    __syncthreads();
    float tot = redB[0];
    #pragma unroll
    for (int i = 1; i < 8; i++) tot += redB[i];
    float al = ex * (1.f/tot);
    if (tid < 256) sa[tid] = al;
    if (tid >= eBase && tid < eBase + eCnt)
      abuf[(tid - eBase)*64 + t] = al;           // buffered; written after loop
    __syncthreads();
    // 8. gates: gacc += alpha . P (split-n over halves; P fully LDS-pinned)
    {
      const half2_t* P2 = (const half2_t*)P_lds;
      const float2*  sap = (const float2*)sa;
      int n2b = half*49;
      #pragma unroll 7
      for (int n2 = n2b; n2 < n2b + 49; n2++) {
        half2_t p = P2[n2*256 + row];
        float2 s2 = sap[n2];
        gacc += s2.x*(float)p[0] + s2.y*(float)p[1];
      }
      sm2[tid] = gacc;
    }
    __syncthreads();
    // 9. pointwise LSTM (c in registers); h buffered in LDS
    if (tid < 64) {
      float ig = sm2[tid]       + sm2[tid + 256];
      float fg = sm2[64 + tid]  + sm2[tid + 320];
      float gg = sm2[128 + tid] + sm2[tid + 384];
      float og = sm2[192 + tid] + sm2[tid + 448];
      float cn = fast_sig(fg)*c_reg + fast_sig(ig)*fast_tanh(gg);
      float hn = fast_sig(og)*fast_tanh(cn);
      c_reg = cn;
      hnl[tid] = hn;
      Hbuf[t*64 + tid] = (_Float16)hn;
    }
    __syncthreads();
    // 10. publish tagged h slice (tag t+1, parity (t+1)&1); no barrier
    if (tid < 32) {
      half2_t h2; h2[0] = (_Float16)hnl[2*tid]; h2[1] = (_Float16)hnl[2*tid+1];
      union { half2_t h; unsigned u; } cv; cv.h = h2;
      AT_ST(hpub64 + ((size_t)((t + 1) & 1)*32 + b)*256 + r*32 + tid,
            ((unsigned long long)(unsigned)(t + 1) << 32) | (unsigned long long)cv.u);
    }
    __syncthreads();
  }

  // bulk-write buffered H and alpha
  for (int i = tid; i < 64*64; i += 512) {
    int t = i >> 6, d = i & 63;
    H_h[((size_t)t*32 + b)*512 + r*64 + d] = Hbuf[i];
  }
  for (int i = tid; i < eCnt*64; i += 512) {
    int ln = i >> 6, tt = i & 63;
    out_alpha[((size_t)b*64 + tt)*196 + eBase + ln] = abuf[ln*64 + tt];
  }
}

// ---- logits: out[b][t][:] = H[t*32+b] @ Wfc^T + bfc ----
// LDS-staged Wfc stripe: each block stages its 128-col x 512-K B-stripe
// (131 KB, +8-half row pad -> 2-way-free banked ds_read_b128) once, then the
// K-loop reads bf from LDS and only af (H, L2/L3-hot) from global.
#define BLD 520   // padded B row stride in halfs
__global__ void __launch_bounds__(512) logits_k(const _Float16* __restrict__ A,
    const _Float16* __restrict__ Bw, float* __restrict__ C,
    const float* __restrict__ bias) {
  __shared__ _Float16 Blds[128*BLD];       // 133120 B
  int tid = threadIdx.x;
  int wave = tid >> 6, lane = tid & 63;
  int lr = lane & 15, quad = lane >> 4;
  int waveM = wave >> 1, waveN = wave & 1;
  int n0base = blockIdx.x*128;
  // stage the Wfc stripe [n0base, n0base+128) x 512 -> LDS (coalesced half8)
  for (int idx = tid; idx < 128*64; idx += 512) {
    int rowL = idx >> 6, col8 = idx & 63;
    *(half8_t*)(Blds + rowL*BLD + col8*8) =
      *(const half8_t*)(Bw + (size_t)(n0base + rowL)*512 + col8*8);
  }
  __syncthreads();
  int n0loc = waveN*64;
  const _Float16* BL = Blds + (n0loc + lr)*BLD + quad*8;
  float bv[4];
  #pragma unroll
  for (int ni = 0; ni < 4; ni++) bv[ni] = bias[n0base + n0loc + ni*16 + lr];
  for (int it = 0; it < 4; ++it) {
    int m0 = (blockIdx.y*16 + it*4 + waveM)*64;
    const _Float16* Ap = A + (size_t)(m0 + lr)*512 + quad*8;
    float4_t acc[4][4];
    #pragma unroll
    for (int i = 0; i < 4; i++)
      #pragma unroll
      for (int j = 0; j < 4; j++)
        acc[i][j] = (float4_t){0.f, 0.f, 0.f, 0.f};
    for (int k0 = 0; k0 < 512; k0 += 32) {
      half8_t af[4], bf[4];
      #pragma unroll
      for (int i = 0; i < 4; i++) af[i] = *(const half8_t*)(Ap + (size_t)i*16*512 + k0);
      #pragma unroll
      for (int i = 0; i < 4; i++) bf[i] = *(const half8_t*)(BL + (size_t)i*16*BLD + k0);
      #pragma unroll
      for (int mi = 0; mi < 4; mi++)
        #pragma unroll
        for (int ni = 0; ni < 4; ni++)
          acc[mi][ni] = __builtin_amdgcn_mfma_f32_16x16x32_f16(af[mi], bf[ni], acc[mi][ni], 0, 0, 0);
    }
    #pragma unroll
    for (int mi = 0; mi < 4; mi++) {
      #pragma unroll
      for (int ni = 0; ni < 4; ni++) {
        int col = n0base + n0loc + ni*16 + lr;
        #pragma unroll
        for (int r = 0; r < 4; r++) {
          int row = m0 + mi*16 + quad*4 + r;
          size_t orow = (size_t)((row & 31)*64 + (row >> 5));
          __builtin_nontemporal_store(acc[mi][ni][r] + bv[ni], C + orow*32000 + col);
        }
      }
    }
  }
}

extern "C" void kernel_launch(void* const* d_in, const int* in_sizes, int n_in,
                              void* d_out, int out_size, void* d_ws, size_t ws_size,
                              hipStream_t stream) {
  const float* imgf  = (const float*)d_in[0];
  const int*   cap   = (const int*)d_in[1];
  const float* emb   = (const float*)d_in[2];
  const float* Wh0   = (const float*)d_in[3];
  const float* bh0   = (const float*)d_in[4];
  const float* Wc0   = (const float*)d_in[5];
  const float* bc0   = (const float*)d_in[6];
  const float* Wenc  = (const float*)d_in[7];
  const float* Wdec  = (const float*)d_in[8];
  const float* v_att = (const float*)d_in[9];
  const float* W_ih  = (const float*)d_in[10];
  const float* b_ih  = (const float*)d_in[11];
  const float* W_hh  = (const float*)d_in[12];
  const float* b_hh  = (const float*)d_in[13];
  const float* Wfc   = (const float*)d_in[14];
  const float* bfc   = (const float*)d_in[15];
  float* out = (float*)d_out;
  (void)in_sizes; (void)n_in; (void)out_size; (void)ws_size;

  char* ws = (char*)d_ws;
  size_t off = 0;
  auto alloc = [&](size_t bytes) -> void* {
    void* p = ws + off;
    off += (bytes + 255) & ~(size_t)255;
    return p;
  };
  _Float16* Wenc_h  = (_Float16*)alloc((size_t)512*512*2);
  _Float16* Wdec_h  = (_Float16*)alloc((size_t)512*512*2);
  _Float16* Wih_h   = (_Float16*)alloc((size_t)2048*1024*2);
  _Float16* Whh_h   = (_Float16*)alloc((size_t)2048*512*2);
  _Float16* Wfc_h   = (_Float16*)alloc((size_t)32000*512*2);
  _Float16* imgf_h  = (_Float16*)alloc((size_t)32*196*512*2);
  _Float16* fproj_T = (_Float16*)alloc((size_t)32*512*PTLD*2);
  _Float16* P_T     = (_Float16*)alloc((size_t)32*2048*PTLD*2);
  _Float16* X_h     = (_Float16*)alloc((size_t)64*32*512*2);
  float*    Xg      = (float*)alloc((size_t)64*32*2048*4);
  float*    bsum    = (float*)alloc((size_t)2048*4);
  float*    c_state = (float*)alloc((size_t)32*512*4);
  unsigned long long* hpub64 = (unsigned long long*)alloc((size_t)2*32*256*8);
  unsigned long long* epub64 = (unsigned long long*)alloc((size_t)2*32*256*8*8);
  _Float16* H_h     = (_Float16*)alloc((size_t)2048*512*2);

  // 1. all converts + gather + bias + tag invalidation (single launch)
  mega_setup_k<<<dim3(2048), dim3(256), 0, stream>>>(
      Wenc, Wenc_h, Wdec, Wdec_h, W_ih, Wih_h, W_hh, Whh_h, Wfc, Wfc_h,
      imgf, imgf_h, emb, cap, X_h, b_ih, b_hh, bsum, hpub64, epub64);
  // 2. h0/c0 (publishes parity-0 tag-0 h words; disjoint from mega's fills)
  init_state_k<<<dim3(32), dim3(256), 0, stream>>>(imgf, Wh0, bh0, Wc0, bc0, c_state, hpub64);
  // 3. fproj_T + P_T + Xg in one launch
  setup_gemms_k<<<dim3(1536), dim3(256), 0, stream>>>(
      Wenc_h, Wih_h, imgf_h, X_h, fproj_T, P_T, Xg, bsum);

  float* out_alpha = out + (size_t)32*64*32000;
  // 4. all 64 recurrence steps: 32 groups x 8 blocks, 512 thr, tag dataflow
  loop_k<<<dim3(256), dim3(512), 0, stream>>>(Wdec_h, Whh_h, fproj_T, P_T, Xg,
      v_att, c_state, hpub64, epub64, H_h, out_alpha);
  // 5. outputs = H @ Wfc^T + bfc (remapped rows; LDS-staged B stripe)
  logits_k<<<dim3(250, 2), dim3(512), 0, stream>>>(H_h, Wfc_h, out, bfc);
}